// Round 9
// baseline (503.081 us; speedup 1.0000x reference)
//
#include <hip/hip_runtime.h>

#define Nn 32
#define Cc 64
#define Vv 25
#define Tt 1024

typedef __attribute__((ext_vector_type(4))) float f32x4;
typedef __attribute__((ext_vector_type(8))) short bf16x8;
typedef __attribute__((ext_vector_type(4))) unsigned short u16x4;

__device__ __forceinline__ unsigned short f2bf(float f) {
    union { float f; unsigned u; } a; a.f = f;
    unsigned u = a.u;
    u += 0x7fff + ((u >> 16) & 1);   // RNE
    return (unsigned short)(u >> 16);
}

__device__ __forceinline__ void gl_lds16(const unsigned short* g, unsigned short* l) {
    __builtin_amdgcn_global_load_lds(
        (const __attribute__((address_space(1))) unsigned int*)g,
        (__attribute__((address_space(3))) unsigned int*)l, 16, 0, 0);
}

// ---------------- fast path ----------------

// xb is stored in MFMA-FRAGMENT ORDER (R8 post-mortem: the old [t][c'] layout
// made every gc B-load a 64-lane 16B scatter across 64 distinct 128B rows --
// ~40% of gc's wall in TA serialization). Chunk (16B = 8 bf16) index:
//   (((n*Vv + w)*4 + sl)*2048) + wv*512 + kc*256 + ni*64 + lane
// where lane = quad*16 + m, and the chunk holds
//   x[c' = (kc*4+quad)*8 + kk][w][t = sl*256 + wv*64 + ni*16 + m], kk=0..7
// i.e. exactly the B fragment lane (m,quad) feeds to MFMA (ni, kc-half).
// gc's B loads become base + lane*16B: fully coalesced.
//
// Fused prep: blocks [0,625) build Weff (XOR-swizzled, unchanged);
// blocks [625,3825) convert one (n,w,sl) 256t x 64c' tile. Loads are
// 4x64B-segment semi-coalesced scalars; stores are 16B x consecutive-lane
// fully coalesced (scatter must NOT migrate to the store side).
__global__ __launch_bounds__(256) void prep_fused(
        const float* __restrict__ x, const float* __restrict__ W,
        const float* __restrict__ A, unsigned short* __restrict__ xb,
        unsigned short* __restrict__ Weff) {
    int bid = blockIdx.x;
    if (bid < Vv * Vv) {
        // ---- Weff part ----
        int v = bid / Vv;
        int w = bid - v * Vv;
        float a0 = A[(0 * Vv + w) * Vv + v];
        float a1 = A[(1 * Vv + w) * Vv + v];
        float a2 = A[(2 * Vv + w) * Vv + v];
        const float* Wb = W + (size_t)w * 192 * 64;
        unsigned short* o = Weff + (size_t)(v * Vv + w) * 4096;
        int c  = threadIdx.x >> 2;
        int c0 = (threadIdx.x & 3) * 16;
        #pragma unroll
        for (int i = 0; i < 16; ++i) {
            int cp = c0 + i;
            float val = a0 * Wb[(c * 3 + 0) * 64 + cp]
                      + a1 * Wb[(c * 3 + 1) * 64 + cp]
                      + a2 * Wb[(c * 3 + 2) * 64 + cp];
            int jl = cp >> 3;
            o[c * 64 + ((jl ^ (c & 7)) << 3) + (cp & 7)] = f2bf(val);
        }
        return;
    }
    // ---- x-convert: one (n, w, sl) tile ----
    int pid = bid - Vv * Vv;
    int n = pid / (Vv * 4);
    int rem = pid - n * (Vv * 4);
    int w = rem >> 2;
    int sl = rem & 3;

    int tid = threadIdx.x;
    int wq = tid >> 6;            // = gc's wv
    int l  = tid & 63;
    int quad = l >> 4, m = l & 15;

    const float* xw = x + ((size_t)n * Cc * Vv + w) * Tt + sl * 256 + wq * 64 + m;
    unsigned short* dst = xb +
        ((((size_t)(n * Vv + w) * 4 + sl) * 2048) + (size_t)wq * 512 + l) * 8;

    #pragma unroll
    for (int kc = 0; kc < 2; ++kc) {
        float vals[4][8];
        #pragma unroll
        for (int kk = 0; kk < 8; ++kk) {
            int cp = (kc * 4 + quad) * 8 + kk;
            const float* row = xw + (size_t)cp * (Vv * Tt);
            #pragma unroll
            for (int ni = 0; ni < 4; ++ni)
                vals[ni][kk] = __builtin_nontemporal_load(row + ni * 16);
        }
        #pragma unroll
        for (int ni = 0; ni < 4; ++ni) {
            bf16x8 o;
            #pragma unroll
            for (int kk = 0; kk < 8; ++kk) o[kk] = (short)f2bf(vals[ni][kk]);
            *(bf16x8*)&dst[(size_t)(kc * 256 + ni * 64) * 8] = o;
        }
    }
}

// out[n, 0:64, v, t0:t0+256] = sum_w Weff[v,w] @ xb[n,w,t0:t0+256,:]
// R8 double-step lockstep pipeline, unchanged schedule/ledger; only the B
// addressing changed (fragment-ordered xb -> base + lane*16B coalesced).
//   - A: global_load_lds into RING-8 LDS (64KB), race-free at distance 2.
//   - B: 3 reg buffers (96 VGPR, survives regalloc; 4 collapse - R7).
//   - One s_barrier per DOUBLE step (13 total).
// Step p (w=2p,2p+1):
//   .1 ISSUE_B(w+2) (8vm)  .2 ISSUE_A(w+4),A(w+5) (4vm)
//   .3 vmcnt(24); s_barrier  .4 COMP(w)  .5 ISSUE_B(w+3) (8vm)
//   .6 vmcnt(20); COMP(w+1)
// Specials: p0 .3=16; p10 .3=22/.6=18; p11 .3=18/.6=10; tail vmcnt(0).
__global__ __launch_bounds__(256, 2) void gc_fast(
        const unsigned short* __restrict__ xb,
        const unsigned short* __restrict__ Weff,
        float* __restrict__ out) {
    __shared__ __align__(16) unsigned short wa[8][4096];   // 64 KB ring-8

    int bid = blockIdx.x;                 // 3200 = 8 xcd * (16 slices * 25 v), v fastest
    int xcd = bid & 7;
    int lid = bid >> 3;
    int v = lid % Vv;
    int s = lid / Vv;                     // 0..15
    int slice = (xcd << 4) + s;           // 0..127
    int n  = slice >> 2;
    int sl = slice & 3;
    int t0 = sl << 8;

    int tid = threadIdx.x;
    int lane = tid & 63, wv = tid >> 6;
    int m = lane & 15, quad = lane >> 4;

    const unsigned short* wg = Weff + (size_t)v * (Vv * 4096);
    // fragment-ordered xb: per (n,w) = 4 sl * 2048 chunks; per w = 65536 shorts
    const unsigned short* xbase = xb + ((size_t)(n * Vv * 4 + sl)) * 2048 * 8;

    int coff0 = ((quad)     ^ (m & 7)) << 3;   // A kc=0 chunk offset (swizzled)
    int coff1 = ((4 + quad) ^ (m & 7)) << 3;   // A kc=1
    int arow[4];
    #pragma unroll
    for (int mi = 0; mi < 4; ++mi) arow[mi] = (mi * 16 + m) * 64;
    int boff[8];
    #pragma unroll
    for (int q = 0; q < 8; ++q) boff[q] = ((wv * 8 + q) * 64 + lane) * 8;

    f32x4 acc[4][4];
    #pragma unroll
    for (int i = 0; i < 4; ++i)
        #pragma unroll
        for (int j = 0; j < 4; ++j)
            acc[i][j] = (f32x4){0.f, 0.f, 0.f, 0.f};

    bf16x8 b0v[8], b1v[8], b2v[8];

#define SB __builtin_amdgcn_sched_barrier(0)
#define VMCNT(N_) asm volatile("s_waitcnt vmcnt(" #N_ ")" ::: "memory")

#define ISSUE_A(WBUF, w_) do { \
    const unsigned short* s_ = wg + (size_t)(w_) * 4096 + tid * 8; \
    gl_lds16(s_,        &wa[WBUF][tid * 8]); \
    gl_lds16(s_ + 2048, &wa[WBUF][2048 + tid * 8]); \
} while (0)

#define ISSUE_B(BN, w_) do { \
    const unsigned short* xw_ = xbase + (size_t)(w_) * 65536; \
    _Pragma("unroll") \
    for (int q_ = 0; q_ < 8; ++q_) \
        BN[q_] = *(const bf16x8*)(xw_ + boff[q_]); \
} while (0)

#define COMP(RBUF, BC) do { \
    const unsigned short* cur_ = &wa[RBUF][0]; \
    bf16x8 af_[8]; \
    _Pragma("unroll") \
    for (int mi_ = 0; mi_ < 4; ++mi_) { \
        af_[mi_]     = *(const bf16x8*)(cur_ + arow[mi_] + coff0); \
        af_[mi_ + 4] = *(const bf16x8*)(cur_ + arow[mi_] + coff1); \
    } \
    __builtin_amdgcn_s_setprio(1); \
    _Pragma("unroll") \
    for (int mi_ = 0; mi_ < 4; ++mi_) \
        _Pragma("unroll") \
        for (int ni_ = 0; ni_ < 4; ++ni_) \
            acc[mi_][ni_] = __builtin_amdgcn_mfma_f32_16x16x32_bf16( \
                af_[mi_], BC[ni_], acc[mi_][ni_], 0, 0, 0); \
    _Pragma("unroll") \
    for (int mi_ = 0; mi_ < 4; ++mi_) \
        _Pragma("unroll") \
        for (int ni_ = 0; ni_ < 4; ++ni_) \
            acc[mi_][ni_] = __builtin_amdgcn_mfma_f32_16x16x32_bf16( \
                af_[mi_ + 4], BC[ni_ + 4], acc[mi_][ni_], 0, 0, 0); \
    __builtin_amdgcn_s_setprio(0); \
} while (0)

#define DSTEP(R0, R1, W4, W5, C0, C1, I2, I3, w_, N3, N6) do { \
    ISSUE_B(I2, (w_) + 2); \
    ISSUE_A(W4, (w_) + 4); \
    ISSUE_A(W5, (w_) + 5); \
    SB; VMCNT(N3); SB; \
    __builtin_amdgcn_s_barrier(); \
    SB; \
    COMP(R0, C0); \
    SB; \
    ISSUE_B(I3, (w_) + 3); \
    SB; VMCNT(N6); SB; \
    COMP(R1, C1); \
    SB; \
} while (0)

    // prologue: B(0)->b0, B(1)->b1 (16 vm); A(0..3)->bufs0..3 (8 vm)
    ISSUE_B(b0v, 0);
    ISSUE_B(b1v, 1);
    ISSUE_A(0, 0);
    ISSUE_A(1, 1);
    ISSUE_A(2, 2);
    ISSUE_A(3, 3);
    SB;

    //     R0 R1 W4 W5  C0   C1   I2   I3   w   N3  N6
    DSTEP(0, 1, 4, 5, b0v, b1v, b2v, b0v,  0, 16, 20);   // p0 (prologue queue)
    DSTEP(2, 3, 6, 7, b2v, b0v, b1v, b2v,  2, 24, 20);   // p1
    DSTEP(4, 5, 0, 1, b1v, b2v, b0v, b1v,  4, 24, 20);   // p2
    DSTEP(6, 7, 2, 3, b0v, b1v, b2v, b0v,  6, 24, 20);   // p3
    DSTEP(0, 1, 4, 5, b2v, b0v, b1v, b2v,  8, 24, 20);   // p4
    DSTEP(2, 3, 6, 7, b1v, b2v, b0v, b1v, 10, 24, 20);   // p5
    DSTEP(4, 5, 0, 1, b0v, b1v, b2v, b0v, 12, 24, 20);   // p6
    DSTEP(6, 7, 2, 3, b2v, b0v, b1v, b2v, 14, 24, 20);   // p7
    DSTEP(0, 1, 4, 5, b1v, b2v, b0v, b1v, 16, 24, 20);   // p8
    DSTEP(2, 3, 6, 7, b0v, b1v, b2v, b0v, 18, 24, 20);   // p9

    // p10: w=20,21. Issues B(22)->b1, A(24)->buf0 (2 vm only), B(23)->b2.
    ISSUE_B(b1v, 22);
    ISSUE_A(0, 24);
    SB; VMCNT(22); SB;
    __builtin_amdgcn_s_barrier();
    SB;
    COMP(4, b2v);
    SB;
    ISSUE_B(b2v, 23);
    SB; VMCNT(18); SB;
    COMP(5, b0v);
    SB;

    // p11: w=22,23. Issues B(24)->b0 only.
    ISSUE_B(b0v, 24);
    SB; VMCNT(18); SB;
    __builtin_amdgcn_s_barrier();
    SB;
    COMP(6, b1v);
    SB; VMCNT(10); SB;
    COMP(7, b2v);
    SB;

    // tail w=24: drain everything (A(24) DMA + B(24)), barrier, compute.
    VMCNT(0);
    SB;
    __builtin_amdgcn_s_barrier();
    SB;
    COMP(0, b0v);

#undef DSTEP
#undef COMP
#undef ISSUE_B
#undef ISSUE_A
#undef VMCNT
#undef SB

    // epilogue: D layout col(t)=lane&15, row(c)=quad*4+reg  (verified in R1)
    // nontemporal: out is write-once, keep xb resident in L2.
    float* og = out + ((size_t)n * Cc * Vv + v) * Tt + t0 + wv * 64 + m;
    #pragma unroll
    for (int mi = 0; mi < 4; ++mi)
        #pragma unroll
        for (int r = 0; r < 4; ++r) {
            int c = mi * 16 + quad * 4 + r;
            float* orow = og + (size_t)c * Vv * Tt;
            #pragma unroll
            for (int ni = 0; ni < 4; ++ni)
                __builtin_nontemporal_store(acc[mi][ni][r], &orow[ni * 16]);
        }
}

// ---------------- fallback path (R1, proven) ----------------

__global__ __launch_bounds__(256) void weff_prep_plain(
        const float* __restrict__ W, const float* __restrict__ A,
        unsigned short* __restrict__ Weff) {
    int v = blockIdx.x / Vv;
    int w = blockIdx.x - v * Vv;
    float a0 = A[(0 * Vv + w) * Vv + v];
    float a1 = A[(1 * Vv + w) * Vv + v];
    float a2 = A[(2 * Vv + w) * Vv + v];
    const float* Wb = W + (size_t)w * 192 * 64;
    unsigned short* o = Weff + (size_t)(v * Vv + w) * 4096;
    int e0 = threadIdx.x * 16;
    #pragma unroll
    for (int i = 0; i < 16; ++i) {
        int e = e0 + i;
        int c = e >> 6, cp = e & 63;
        float val = a0 * Wb[(c * 3 + 0) * 64 + cp]
                  + a1 * Wb[(c * 3 + 1) * 64 + cp]
                  + a2 * Wb[(c * 3 + 2) * 64 + cp];
        o[e] = f2bf(val);
    }
}

__global__ __launch_bounds__(256, 2) void gc_plain(
        const float* __restrict__ x, const unsigned short* __restrict__ Weff,
        float* __restrict__ out) {
    __shared__ __align__(16) unsigned short xs[256 * 72];
    __shared__ __align__(16) unsigned short wa[64 * 72];
    int bid = blockIdx.x;
    int xcd = bid & 7;
    int lid = bid >> 3;
    int v, s;
    if (lid < 13 * 16) { v = lid % 13;            s = lid / 13; }
    else { int l2 = lid - 13 * 16; v = 13 + l2 % 12; s = l2 / 12; }
    int slice = (xcd << 4) + s;
    int n  = slice >> 2;
    int t0 = (slice & 3) << 8;
    int tid  = threadIdx.x;
    int lane = tid & 63;
    int wv   = tid >> 6;
    int m    = lane & 15;
    int quad = lane >> 4;
    int cc = tid & 7;
    int tt = tid >> 3;
    f32x4 acc[4][4];
    #pragma unroll
    for (int i = 0; i < 4; ++i)
        #pragma unroll
        for (int j = 0; j < 4; ++j)
            acc[i][j] = (f32x4){0.f, 0.f, 0.f, 0.f};
    const float* xg = x + (size_t)n * Cc * Vv * Tt + t0 + tt * 4;
    const bf16x8* wg = (const bf16x8*)(Weff + (size_t)v * Vv * 4096);
    for (int w = 0; w < Vv; ++w) {
        if (w) __syncthreads();
        #pragma unroll
        for (int r = 0; r < 2; ++r) {
            int q = r * 256 + tid;
            int c = q >> 3, b = q & 7;
            *(bf16x8*)&wa[c * 72 + b * 8] = wg[w * 512 + q];
        }
        {
            bf16x8 rows[8];
            #pragma unroll
            for (int i = 0; i < 8; ++i) {
                int cp = cc * 8 + i;
                const float* p = xg + ((size_t)cp * Vv + w) * Tt;
                float4 f0 = *(const float4*)p;
                float4 f1 = *(const float4*)(p + 128);
                rows[0][i] = (short)f2bf(f0.x); rows[1][i] = (short)f2bf(f0.y);
                rows[2][i] = (short)f2bf(f0.z); rows[3][i] = (short)f2bf(f0.w);
                rows[4][i] = (short)f2bf(f1.x); rows[5][i] = (short)f2bf(f1.y);
                rows[6][i] = (short)f2bf(f1.z); rows[7][i] = (short)f2bf(f1.w);
            }
            #pragma unroll
            for (int j = 0; j < 4; ++j) {
                *(bf16x8*)&xs[(tt * 4 + j) * 72 + cc * 8]       = rows[j];
                *(bf16x8*)&xs[(128 + tt * 4 + j) * 72 + cc * 8] = rows[4 + j];
            }
        }
        __syncthreads();
        #pragma unroll
        for (int kc = 0; kc < 2; ++kc) {
            int ko = kc * 32 + quad * 8;
            bf16x8 afr[4], bfr[4];
            #pragma unroll
            for (int mi = 0; mi < 4; ++mi)
                afr[mi] = *(const bf16x8*)&wa[(mi * 16 + m) * 72 + ko];
            #pragma unroll
            for (int ni = 0; ni < 4; ++ni)
                bfr[ni] = *(const bf16x8*)&xs[(wv * 64 + ni * 16 + m) * 72 + ko];
            #pragma unroll
            for (int mi = 0; mi < 4; ++mi)
                #pragma unroll
                for (int ni = 0; ni < 4; ++ni)
                    acc[mi][ni] = __builtin_amdgcn_mfma_f32_16x16x32_bf16(
                        afr[mi], bfr[ni], acc[mi][ni], 0, 0, 0);
        }
    }
    float* og = out + ((size_t)n * Cc * Vv + v) * Tt + t0 + wv * 64 + m;
    #pragma unroll
    for (int mi = 0; mi < 4; ++mi)
        #pragma unroll
        for (int r = 0; r < 4; ++r) {
            int c = mi * 16 + quad * 4 + r;
            float* orow = og + (size_t)c * Vv * Tt;
            #pragma unroll
            for (int ni = 0; ni < 4; ++ni)
                orow[ni * 16] = acc[mi][ni][r];
        }
}

extern "C" void kernel_launch(void* const* d_in, const int* in_sizes, int n_in,
                              void* d_out, int out_size, void* d_ws, size_t ws_size,
                              hipStream_t stream) {
    const float* x = (const float*)d_in[0];   // [32,64,25,1024]
    const float* W = (const float*)d_in[1];   // [25,192,64]
    const float* A = (const float*)d_in[2];   // [3,25,25]
    float* out = (float*)d_out;

    const size_t xb_elems   = (size_t)Nn * Vv * Tt * 64;       // 52,428,800
    const size_t weff_elems = (size_t)Vv * Vv * 4096;          //  2,560,000
    const size_t need = (xb_elems + weff_elems) * sizeof(unsigned short);

    if (ws_size >= need) {
        unsigned short* xb   = (unsigned short*)d_ws;
        unsigned short* Weff = xb + xb_elems;
        prep_fused<<<dim3(Vv * Vv + Nn * Vv * 4), dim3(256), 0, stream>>>(x, W, A, xb, Weff);
        gc_fast<<<dim3(3200), dim3(256), 0, stream>>>(xb, Weff, out);
    } else {
        unsigned short* Weff = (unsigned short*)d_ws;
        weff_prep_plain<<<dim3(Vv * Vv), dim3(256), 0, stream>>>(W, A, Weff);
        gc_plain<<<dim3(3200), dim3(256), 0, stream>>>(x, Weff, out);
    }
}

// Round 10
// 490.283 us; speedup vs baseline: 1.0261x; 1.0261x over previous
//
#include <hip/hip_runtime.h>

#define Nn 32
#define Cc 64
#define Vv 25
#define Tt 1024

typedef __attribute__((ext_vector_type(4))) float f32x4;
typedef __attribute__((ext_vector_type(8))) short bf16x8;
typedef __attribute__((ext_vector_type(4))) unsigned short u16x4;

__device__ __forceinline__ unsigned short f2bf(float f) {
    union { float f; unsigned u; } a; a.f = f;
    unsigned u = a.u;
    u += 0x7fff + ((u >> 16) & 1);   // RNE
    return (unsigned short)(u >> 16);
}

__device__ __forceinline__ void gl_lds16(const unsigned short* g, unsigned short* l) {
    __builtin_amdgcn_global_load_lds(
        (const __attribute__((address_space(1))) unsigned int*)g,
        (__attribute__((address_space(3))) unsigned int*)l, 16, 0, 0);
}

// ---------------- fast path ----------------

// xb in MFMA-FRAGMENT ORDER (R9): chunk (16B) index
//   (((n*Vv + w)*4 + sl)*2048) + wv*512 + kc*256 + ni*64 + lane
// -> gc's B loads are base + lane*16B, fully coalesced.
// Fused prep: blocks [0,625) build Weff (XOR-swizzled); blocks [625,3825)
// convert one (n,w,sl) 256t x 64c' tile (loads 4x64B-segment semi-coalesced,
// stores fully coalesced).
__global__ __launch_bounds__(256) void prep_fused(
        const float* __restrict__ x, const float* __restrict__ W,
        const float* __restrict__ A, unsigned short* __restrict__ xb,
        unsigned short* __restrict__ Weff) {
    int bid = blockIdx.x;
    if (bid < Vv * Vv) {
        // ---- Weff part ----
        int v = bid / Vv;
        int w = bid - v * Vv;
        float a0 = A[(0 * Vv + w) * Vv + v];
        float a1 = A[(1 * Vv + w) * Vv + v];
        float a2 = A[(2 * Vv + w) * Vv + v];
        const float* Wb = W + (size_t)w * 192 * 64;
        unsigned short* o = Weff + (size_t)(v * Vv + w) * 4096;
        int c  = threadIdx.x >> 2;
        int c0 = (threadIdx.x & 3) * 16;
        #pragma unroll
        for (int i = 0; i < 16; ++i) {
            int cp = c0 + i;
            float val = a0 * Wb[(c * 3 + 0) * 64 + cp]
                      + a1 * Wb[(c * 3 + 1) * 64 + cp]
                      + a2 * Wb[(c * 3 + 2) * 64 + cp];
            int jl = cp >> 3;
            o[c * 64 + ((jl ^ (c & 7)) << 3) + (cp & 7)] = f2bf(val);
        }
        return;
    }
    // ---- x-convert: one (n, w, sl) tile ----
    int pid = bid - Vv * Vv;
    int n = pid / (Vv * 4);
    int rem = pid - n * (Vv * 4);
    int w = rem >> 2;
    int sl = rem & 3;

    int tid = threadIdx.x;
    int wq = tid >> 6;            // = gc's wv
    int l  = tid & 63;
    int quad = l >> 4, m = l & 15;

    const float* xw = x + ((size_t)n * Cc * Vv + w) * Tt + sl * 256 + wq * 64 + m;
    unsigned short* dst = xb +
        ((((size_t)(n * Vv + w) * 4 + sl) * 2048) + (size_t)wq * 512 + l) * 8;

    #pragma unroll
    for (int kc = 0; kc < 2; ++kc) {
        float vals[4][8];
        #pragma unroll
        for (int kk = 0; kk < 8; ++kk) {
            int cp = (kc * 4 + quad) * 8 + kk;
            const float* row = xw + (size_t)cp * (Vv * Tt);
            #pragma unroll
            for (int ni = 0; ni < 4; ++ni)
                vals[ni][kk] = __builtin_nontemporal_load(row + ni * 16);
        }
        #pragma unroll
        for (int ni = 0; ni < 4; ++ni) {
            bf16x8 o;
            #pragma unroll
            for (int kk = 0; kk < 8; ++kk) o[kk] = (short)f2bf(vals[ni][kk]);
            *(bf16x8*)&dst[(size_t)(kc * 256 + ni * 64) * 8] = o;
        }
    }
}

// out[n, 0:64, v, t0:t0+256] = sum_w Weff[v,w] @ xb[n,w,t0:t0+256,:]
// R10: A-FRAGMENT PRELOAD. R3-R9 all pinned at ~35% MfmaUtil because every
// step's critical path was barrier -> 8 ds_read_b128 (64KB/CU burst, ~770cy)
// -> MFMA. Now the af regs for step w are read during step w-1, so COMP is
// pure-register MFMA starting right after the barrier; the ds_reads for w+1
// issue after COMP(w) and overlap the next barrier wait.
//   A: global_load_lds -> RING-4 LDS (32KB); B: 3 reg bufs (R9 coalesced).
// Ledger (A issued BEFORE B each step; uniform): at step w, outstanding
// before wait = B(w)8 [w-2] + A(w+1)2,B(w+1)8 [w-1] + A(w+2)2,B(w+2)8 [w]
// = 28 -> vmcnt(18) drains exactly B(w) (COMP) + A(w+1) (LDREAD). Ring-4
// safe: buf rewritten at w was last ds_read at w-3's tail, 2 barriers back.
// Specials: prologue vmcnt(16); w=23 vmcnt(8); w=24 vmcnt(0), no barrier.
__global__ __launch_bounds__(256, 2) void gc_fast(
        const unsigned short* __restrict__ xb,
        const unsigned short* __restrict__ Weff,
        float* __restrict__ out) {
    __shared__ __align__(16) unsigned short wa[4][4096];   // 32 KB ring-4

    int bid = blockIdx.x;                 // 3200 = 8 xcd * (16 slices * 25 v), v fastest
    int xcd = bid & 7;
    int lid = bid >> 3;
    int v = lid % Vv;
    int s = lid / Vv;                     // 0..15
    int slice = (xcd << 4) + s;           // 0..127
    int n  = slice >> 2;
    int sl = slice & 3;
    int t0 = sl << 8;

    int tid = threadIdx.x;
    int lane = tid & 63, wv = tid >> 6;
    int m = lane & 15, quad = lane >> 4;

    const unsigned short* wg = Weff + (size_t)v * (Vv * 4096);
    const unsigned short* xbase = xb + ((size_t)(n * Vv * 4 + sl)) * 2048 * 8;

    int coff0 = ((quad)     ^ (m & 7)) << 3;   // A kc=0 chunk offset (swizzled)
    int coff1 = ((4 + quad) ^ (m & 7)) << 3;   // A kc=1
    int arow[4];
    #pragma unroll
    for (int mi = 0; mi < 4; ++mi) arow[mi] = (mi * 16 + m) * 64;
    int boff[8];
    #pragma unroll
    for (int q = 0; q < 8; ++q) boff[q] = ((wv * 8 + q) * 64 + lane) * 8;

    f32x4 acc[4][4];
    #pragma unroll
    for (int i = 0; i < 4; ++i)
        #pragma unroll
        for (int j = 0; j < 4; ++j)
            acc[i][j] = (f32x4){0.f, 0.f, 0.f, 0.f};

    bf16x8 b0v[8], b1v[8], b2v[8];
    bf16x8 afA[8], afB[8];

#define SB __builtin_amdgcn_sched_barrier(0)
#define VMCNT(N_) asm volatile("s_waitcnt vmcnt(" #N_ ")" ::: "memory")

#define ISSUE_A(WBUF, w_) do { \
    const unsigned short* s_ = wg + (size_t)(w_) * 4096 + tid * 8; \
    gl_lds16(s_,        &wa[WBUF][tid * 8]); \
    gl_lds16(s_ + 2048, &wa[WBUF][2048 + tid * 8]); \
} while (0)

#define ISSUE_B(BN, w_) do { \
    const unsigned short* xw_ = xbase + (size_t)(w_) * 65536; \
    _Pragma("unroll") \
    for (int q_ = 0; q_ < 8; ++q_) \
        BN[q_] = *(const bf16x8*)(xw_ + boff[q_]); \
} while (0)

#define LDREAD(AF, RBUF) do { \
    const unsigned short* cur_ = &wa[RBUF][0]; \
    _Pragma("unroll") \
    for (int mi_ = 0; mi_ < 4; ++mi_) { \
        AF[mi_]     = *(const bf16x8*)(cur_ + arow[mi_] + coff0); \
        AF[mi_ + 4] = *(const bf16x8*)(cur_ + arow[mi_] + coff1); \
    } \
} while (0)

#define COMP(AF, BC) do { \
    __builtin_amdgcn_s_setprio(1); \
    _Pragma("unroll") \
    for (int mi_ = 0; mi_ < 4; ++mi_) \
        _Pragma("unroll") \
        for (int ni_ = 0; ni_ < 4; ++ni_) \
            acc[mi_][ni_] = __builtin_amdgcn_mfma_f32_16x16x32_bf16( \
                AF[mi_], BC[ni_], acc[mi_][ni_], 0, 0, 0); \
    _Pragma("unroll") \
    for (int mi_ = 0; mi_ < 4; ++mi_) \
        _Pragma("unroll") \
        for (int ni_ = 0; ni_ < 4; ++ni_) \
            acc[mi_][ni_] = __builtin_amdgcn_mfma_f32_16x16x32_bf16( \
                AF[mi_ + 4], BC[ni_ + 4], acc[mi_][ni_], 0, 0, 0); \
    __builtin_amdgcn_s_setprio(0); \
} while (0)

// Step w: issue A(w+2) then B(w+2); vmcnt(18); barrier; COMP(w) pure-reg;
// ds_read af(w+1) from buf RB=(w+1)%4 (overlaps next barrier wait).
#define STEP(AFc, AFn, WB, RB, BC, BN, w_) do { \
    ISSUE_A(WB, (w_) + 2); \
    ISSUE_B(BN, (w_) + 2); \
    SB; VMCNT(18); SB; \
    __builtin_amdgcn_s_barrier(); \
    SB; \
    COMP(AFc, BC); \
    LDREAD(AFn, RB); \
    SB; \
} while (0)

    // prologue: A(0)->buf0, A(1)->buf1 (4 vm, oldest), B(0)->b0, B(1)->b1 (16 vm)
    ISSUE_A(0, 0);
    ISSUE_A(1, 1);
    ISSUE_B(b0v, 0);
    ISSUE_B(b1v, 1);
    SB; VMCNT(16); SB;          // drains A(0),A(1); keeps B(0),B(1)
    __builtin_amdgcn_s_barrier();
    SB;
    LDREAD(afA, 0);             // af(0)
    SB;

    //   AFc  AFn  WB RB  BC   BN   w
    STEP(afA, afB, 2, 1, b0v, b2v,  0);
    STEP(afB, afA, 3, 2, b1v, b0v,  1);
    STEP(afA, afB, 0, 3, b2v, b1v,  2);
    STEP(afB, afA, 1, 0, b0v, b2v,  3);
    STEP(afA, afB, 2, 1, b1v, b0v,  4);
    STEP(afB, afA, 3, 2, b2v, b1v,  5);
    STEP(afA, afB, 0, 3, b0v, b2v,  6);
    STEP(afB, afA, 1, 0, b1v, b0v,  7);
    STEP(afA, afB, 2, 1, b2v, b1v,  8);
    STEP(afB, afA, 3, 2, b0v, b2v,  9);
    STEP(afA, afB, 0, 3, b1v, b0v, 10);
    STEP(afB, afA, 1, 0, b2v, b1v, 11);
    STEP(afA, afB, 2, 1, b0v, b2v, 12);
    STEP(afB, afA, 3, 2, b1v, b0v, 13);
    STEP(afA, afB, 0, 3, b2v, b1v, 14);
    STEP(afB, afA, 1, 0, b0v, b2v, 15);
    STEP(afA, afB, 2, 1, b1v, b0v, 16);
    STEP(afB, afA, 3, 2, b2v, b1v, 17);
    STEP(afA, afB, 0, 3, b0v, b2v, 18);
    STEP(afB, afA, 1, 0, b1v, b0v, 19);
    STEP(afA, afB, 2, 1, b2v, b1v, 20);
    STEP(afB, afA, 3, 2, b0v, b2v, 21);
    STEP(afA, afB, 0, 3, b1v, b0v, 22);
    // w=23 (no issues): outstanding = B(23)8 [w21] + A(24)2,B(24)8 [w22].
    // vmcnt(8) drains B(23) (COMP) + A(24) (LDREAD); keeps B(24).
    SB; VMCNT(8); SB;
    __builtin_amdgcn_s_barrier();
    SB;
    COMP(afB, b2v);
    LDREAD(afA, 0);             // af(24); A(24) in LDS (vmcnt(8)+barrier)
    SB;
    // w=24: drain B(24); no barrier needed (no LDS writer remains).
    VMCNT(0);
    SB;
    COMP(afA, b0v);

#undef STEP
#undef COMP
#undef LDREAD
#undef ISSUE_B
#undef ISSUE_A
#undef VMCNT
#undef SB

    // epilogue: D layout col(t)=lane&15, row(c)=quad*4+reg  (verified in R1)
    // nontemporal: out is write-once, keep xb resident in L2.
    float* og = out + ((size_t)n * Cc * Vv + v) * Tt + t0 + wv * 64 + m;
    #pragma unroll
    for (int mi = 0; mi < 4; ++mi)
        #pragma unroll
        for (int r = 0; r < 4; ++r) {
            int c = mi * 16 + quad * 4 + r;
            float* orow = og + (size_t)c * Vv * Tt;
            #pragma unroll
            for (int ni = 0; ni < 4; ++ni)
                __builtin_nontemporal_store(acc[mi][ni][r], &orow[ni * 16]);
        }
}

// ---------------- fallback path (R1, proven) ----------------

__global__ __launch_bounds__(256) void weff_prep_plain(
        const float* __restrict__ W, const float* __restrict__ A,
        unsigned short* __restrict__ Weff) {
    int v = blockIdx.x / Vv;
    int w = blockIdx.x - v * Vv;
    float a0 = A[(0 * Vv + w) * Vv + v];
    float a1 = A[(1 * Vv + w) * Vv + v];
    float a2 = A[(2 * Vv + w) * Vv + v];
    const float* Wb = W + (size_t)w * 192 * 64;
    unsigned short* o = Weff + (size_t)(v * Vv + w) * 4096;
    int e0 = threadIdx.x * 16;
    #pragma unroll
    for (int i = 0; i < 16; ++i) {
        int e = e0 + i;
        int c = e >> 6, cp = e & 63;
        float val = a0 * Wb[(c * 3 + 0) * 64 + cp]
                  + a1 * Wb[(c * 3 + 1) * 64 + cp]
                  + a2 * Wb[(c * 3 + 2) * 64 + cp];
        o[e] = f2bf(val);
    }
}

__global__ __launch_bounds__(256, 2) void gc_plain(
        const float* __restrict__ x, const unsigned short* __restrict__ Weff,
        float* __restrict__ out) {
    __shared__ __align__(16) unsigned short xs[256 * 72];
    __shared__ __align__(16) unsigned short wa[64 * 72];
    int bid = blockIdx.x;
    int xcd = bid & 7;
    int lid = bid >> 3;
    int v, s;
    if (lid < 13 * 16) { v = lid % 13;            s = lid / 13; }
    else { int l2 = lid - 13 * 16; v = 13 + l2 % 12; s = l2 / 12; }
    int slice = (xcd << 4) + s;
    int n  = slice >> 2;
    int t0 = (slice & 3) << 8;
    int tid  = threadIdx.x;
    int lane = tid & 63;
    int wv   = tid >> 6;
    int m    = lane & 15;
    int quad = lane >> 4;
    int cc = tid & 7;
    int tt = tid >> 3;
    f32x4 acc[4][4];
    #pragma unroll
    for (int i = 0; i < 4; ++i)
        #pragma unroll
        for (int j = 0; j < 4; ++j)
            acc[i][j] = (f32x4){0.f, 0.f, 0.f, 0.f};
    const float* xg = x + (size_t)n * Cc * Vv * Tt + t0 + tt * 4;
    const bf16x8* wg = (const bf16x8*)(Weff + (size_t)v * Vv * 4096);
    for (int w = 0; w < Vv; ++w) {
        if (w) __syncthreads();
        #pragma unroll
        for (int r = 0; r < 2; ++r) {
            int q = r * 256 + tid;
            int c = q >> 3, b = q & 7;
            *(bf16x8*)&wa[c * 72 + b * 8] = wg[w * 512 + q];
        }
        {
            bf16x8 rows[8];
            #pragma unroll
            for (int i = 0; i < 8; ++i) {
                int cp = cc * 8 + i;
                const float* p = xg + ((size_t)cp * Vv + w) * Tt;
                float4 f0 = *(const float4*)p;
                float4 f1 = *(const float4*)(p + 128);
                rows[0][i] = (short)f2bf(f0.x); rows[1][i] = (short)f2bf(f0.y);
                rows[2][i] = (short)f2bf(f0.z); rows[3][i] = (short)f2bf(f0.w);
                rows[4][i] = (short)f2bf(f1.x); rows[5][i] = (short)f2bf(f1.y);
                rows[6][i] = (short)f2bf(f1.z); rows[7][i] = (short)f2bf(f1.w);
            }
            #pragma unroll
            for (int j = 0; j < 4; ++j) {
                *(bf16x8*)&xs[(tt * 4 + j) * 72 + cc * 8]       = rows[j];
                *(bf16x8*)&xs[(128 + tt * 4 + j) * 72 + cc * 8] = rows[4 + j];
            }
        }
        __syncthreads();
        #pragma unroll
        for (int kc = 0; kc < 2; ++kc) {
            int ko = kc * 32 + quad * 8;
            bf16x8 afr[4], bfr[4];
            #pragma unroll
            for (int mi = 0; mi < 4; ++mi)
                afr[mi] = *(const bf16x8*)&wa[(mi * 16 + m) * 72 + ko];
            #pragma unroll
            for (int ni = 0; ni < 4; ++ni)
                bfr[ni] = *(const bf16x8*)&xs[(wv * 64 + ni * 16 + m) * 72 + ko];
            #pragma unroll
            for (int mi = 0; mi < 4; ++mi)
                #pragma unroll
                for (int ni = 0; ni < 4; ++ni)
                    acc[mi][ni] = __builtin_amdgcn_mfma_f32_16x16x32_bf16(
                        afr[mi], bfr[ni], acc[mi][ni], 0, 0, 0);
        }
    }
    float* og = out + ((size_t)n * Cc * Vv + v) * Tt + t0 + wv * 64 + m;
    #pragma unroll
    for (int mi = 0; mi < 4; ++mi)
        #pragma unroll
        for (int r = 0; r < 4; ++r) {
            int c = mi * 16 + quad * 4 + r;
            float* orow = og + (size_t)c * Vv * Tt;
            #pragma unroll
            for (int ni = 0; ni < 4; ++ni)
                orow[ni * 16] = acc[mi][ni][r];
        }
}

extern "C" void kernel_launch(void* const* d_in, const int* in_sizes, int n_in,
                              void* d_out, int out_size, void* d_ws, size_t ws_size,
                              hipStream_t stream) {
    const float* x = (const float*)d_in[0];   // [32,64,25,1024]
    const float* W = (const float*)d_in[1];   // [25,192,64]
    const float* A = (const float*)d_in[2];   // [3,25,25]
    float* out = (float*)d_out;

    const size_t xb_elems   = (size_t)Nn * Vv * Tt * 64;       // 52,428,800
    const size_t weff_elems = (size_t)Vv * Vv * 4096;          //  2,560,000
    const size_t need = (xb_elems + weff_elems) * sizeof(unsigned short);

    if (ws_size >= need) {
        unsigned short* xb   = (unsigned short*)d_ws;
        unsigned short* Weff = xb + xb_elems;
        prep_fused<<<dim3(Vv * Vv + Nn * Vv * 4), dim3(256), 0, stream>>>(x, W, A, xb, Weff);
        gc_fast<<<dim3(3200), dim3(256), 0, stream>>>(xb, Weff, out);
    } else {
        unsigned short* Weff = (unsigned short*)d_ws;
        weff_prep_plain<<<dim3(Vv * Vv), dim3(256), 0, stream>>>(W, A, Weff);
        gc_plain<<<dim3(3200), dim3(256), 0, stream>>>(x, Weff, out);
    }
}